// Round 1
// baseline (503.566 us; speedup 1.0000x reference)
//
#include <hip/hip_runtime.h>
#include <hip/hip_fp16.h>

#define MAX_SEQ 2048
#define HEAD_NUM 8

typedef float vfloat4 __attribute__((ext_vector_type(4)));
typedef int   vint4   __attribute__((ext_vector_type(4)));

// R5: read-once / write-8 head fan-out.
// One block = 1024 consecutive elements of one batch's s*s CROP.
// Each thread: one float4 load + fp16-RTNE compare -> int4, then 8
// nontemporal int4 stores, one per head copy (stride ss in the output).
// Reads drop to the compulsory 53.5 MB (no re-read across heads);
// writes stay the compulsory 427.8 MB, fully coalesced (1KB/wave/store).
__global__ __launch_bounds__(256) void genmask_kernel(
    const float* __restrict__ mask,   // (8, 1, 2048, 2048) f32
    int*         __restrict__ out)    // packed int32 0/1 (bool)
{
    // seq_lengths = {2048,1792,1536,1280,1024,768,512,256}
    constexpr unsigned int S[8]  = {2048u,1792u,1536u,1280u,1024u,768u,512u,256u};
    constexpr unsigned int SS[8] = {4194304u,3211264u,2359296u,1638400u,
                                    1048576u,589824u,262144u,65536u};
    // cumulative 1024-elem chunks per batch CROP (ss/1024 each:
    // 4096,3136,2304,1600,1024,576,256,64 -> total 13056 blocks)
    constexpr unsigned int CS[8] = {0u,4096u,7232u,9536u,11136u,
                                    12160u,12736u,12992u};
    // cumulative output element offsets per batch region (8*ss each)
    constexpr unsigned long long ES[8] = {0ull,33554432ull,59244544ull,
        78118912ull,91226112ull,99614720ull,104333312ull,106430464ull};
    // exact magic for rem/s: i=(rem*M)>>40, M=floor(2^40/s)+1
    // (verified absmax=0 on full data in prior rounds, same rem domain [0,ss))
    constexpr unsigned long long MG[8] = {(1ull<<29)+1, 613566757ull,
        715827883ull, 858993460ull, (1ull<<30)+1, 1431655766ull,
        (1ull<<31)+1, (1ull<<32)+1};

    const unsigned int blk = blockIdx.x;

    // Branchless batch lookup on immediates (wave-uniform).
    int b = 0;
    #pragma unroll
    for (int t = 1; t < 8; ++t) b += (blk >= CS[t]) ? 1 : 0;

    const unsigned int s  = S[b];
    const unsigned int ss = SS[b];

    // Element offset within this batch's crop [0, ss).
    const unsigned int rem = (blk - CS[b]) * 1024u + threadIdx.x * 4u;
    const unsigned int i = (unsigned int)(((unsigned long long)rem * MG[b]) >> 40);
    const unsigned int j = rem - i * s;      // multiple of 4

    const vfloat4 v = *(const vfloat4*)(mask
        + (size_t)b * MAX_SEQ * MAX_SEQ + (size_t)i * MAX_SEQ + j);

    const __half half_pt5 = __float2half(0.5f);
    vint4 r;
    r.x = __hgt(__float2half(v.x), half_pt5) ? 1 : 0;
    r.y = __hgt(__float2half(v.y), half_pt5) ? 1 : 0;
    r.z = __hgt(__float2half(v.z), half_pt5) ? 1 : 0;
    r.w = __hgt(__float2half(v.w), half_pt5) ? 1 : 0;

    // Fan out to the 8 head copies: out + ES[b] + h*ss + rem.
    // ss and ES[b] are multiples of 1024, rem a multiple of 4 ->
    // every store stays 16B-aligned.
    int* p = out + ES[b] + rem;
    #pragma unroll
    for (int h = 0; h < HEAD_NUM; ++h) {
        __builtin_nontemporal_store(r, (vint4*)p);
        p += ss;
    }
}

extern "C" void kernel_launch(void* const* d_in, const int* in_sizes, int n_in,
                              void* d_out, int out_size, void* d_ws, size_t ws_size,
                              hipStream_t stream) {
    const float* mask = (const float*)d_in[0];
    int*         out  = (int*)d_out;

    // out_size = 106,954,752 elements; 1024 crop-elements per block,
    // each block writes 8 head copies -> out_size / (1024*8) = 13056 blocks.
    const unsigned int n_blocks = (unsigned int)(out_size / (1024 * HEAD_NUM));

    genmask_kernel<<<n_blocks, 256, 0, stream>>>(mask, out);
}

// Round 2
// 499.170 us; speedup vs baseline: 1.0088x; 1.0088x over previous
//
#include <hip/hip_runtime.h>
#include <hip/hip_fp16.h>

#define MAX_SEQ 2048
#define HEAD_NUM 8

typedef float vfloat4 __attribute__((ext_vector_type(4)));
typedef int   vint4   __attribute__((ext_vector_type(4)));

// R6: read-once / write-8 head fan-out, PLAIN (cached) stores.
// Theory: __builtin_nontemporal_store bypasses L2 (the write-combining
// point) and amplifies the 427.8 MB write stream ~2-4x on the HBM bus --
// the measured ~208 us kernel vs the ~76 us compulsory-traffic floor.
// The fan-out mapping reads each input byte exactly once, so we don't
// need nt's cache-pollution protection: let writes coalesce in L2/L3.
// One block = 1024 consecutive elements of one batch's s*s CROP.
// Each thread: one float4 load + fp16-RTNE compare -> int4, then 8
// plain int4 stores, one per head copy (stride ss in the output).
__global__ __launch_bounds__(256) void genmask_kernel(
    const float* __restrict__ mask,   // (8, 1, 2048, 2048) f32
    int*         __restrict__ out)    // packed int32 0/1 (bool)
{
    // seq_lengths = {2048,1792,1536,1280,1024,768,512,256}
    constexpr unsigned int S[8]  = {2048u,1792u,1536u,1280u,1024u,768u,512u,256u};
    constexpr unsigned int SS[8] = {4194304u,3211264u,2359296u,1638400u,
                                    1048576u,589824u,262144u,65536u};
    // cumulative 1024-elem chunks per batch CROP (ss/1024 each:
    // 4096,3136,2304,1600,1024,576,256,64 -> total 13056 blocks)
    constexpr unsigned int CS[8] = {0u,4096u,7232u,9536u,11136u,
                                    12160u,12736u,12992u};
    // cumulative output element offsets per batch region (8*ss each)
    constexpr unsigned long long ES[8] = {0ull,33554432ull,59244544ull,
        78118912ull,91226112ull,99614720ull,104333312ull,106430464ull};
    // exact magic for rem/s: i=(rem*M)>>40, M=floor(2^40/s)+1
    // (verified absmax=0 on full data in prior rounds, same rem domain [0,ss))
    constexpr unsigned long long MG[8] = {(1ull<<29)+1, 613566757ull,
        715827883ull, 858993460ull, (1ull<<30)+1, 1431655766ull,
        (1ull<<31)+1, (1ull<<32)+1};

    const unsigned int blk = blockIdx.x;

    // Branchless batch lookup on immediates (wave-uniform).
    int b = 0;
    #pragma unroll
    for (int t = 1; t < 8; ++t) b += (blk >= CS[t]) ? 1 : 0;

    const unsigned int s  = S[b];
    const unsigned int ss = SS[b];

    // Element offset within this batch's crop [0, ss).
    const unsigned int rem = (blk - CS[b]) * 1024u + threadIdx.x * 4u;
    const unsigned int i = (unsigned int)(((unsigned long long)rem * MG[b]) >> 40);
    const unsigned int j = rem - i * s;      // multiple of 4

    const vfloat4 v = *(const vfloat4*)(mask
        + (size_t)b * MAX_SEQ * MAX_SEQ + (size_t)i * MAX_SEQ + j);

    const __half half_pt5 = __float2half(0.5f);
    vint4 r;
    r.x = __hgt(__float2half(v.x), half_pt5) ? 1 : 0;
    r.y = __hgt(__float2half(v.y), half_pt5) ? 1 : 0;
    r.z = __hgt(__float2half(v.z), half_pt5) ? 1 : 0;
    r.w = __hgt(__float2half(v.w), half_pt5) ? 1 : 0;

    // Fan out to the 8 head copies: out + ES[b] + h*ss + rem.
    // ss and ES[b] are multiples of 1024, rem a multiple of 4 ->
    // every store stays 16B-aligned. Plain stores: coalesce in L2.
    int* p = out + ES[b] + rem;
    #pragma unroll
    for (int h = 0; h < HEAD_NUM; ++h) {
        *(vint4*)p = r;
        p += ss;
    }
}

extern "C" void kernel_launch(void* const* d_in, const int* in_sizes, int n_in,
                              void* d_out, int out_size, void* d_ws, size_t ws_size,
                              hipStream_t stream) {
    const float* mask = (const float*)d_in[0];
    int*         out  = (int*)d_out;

    // out_size = 106,954,752 elements; 1024 crop-elements per block,
    // each block writes 8 head copies -> out_size / (1024*8) = 13056 blocks.
    const unsigned int n_blocks = (unsigned int)(out_size / (1024 * HEAD_NUM));

    genmask_kernel<<<n_blocks, 256, 0, stream>>>(mask, out);
}

// Round 3
// 496.122 us; speedup vs baseline: 1.0150x; 1.0061x over previous
//
#include <hip/hip_runtime.h>
#include <hip/hip_fp16.h>

#define MAX_SEQ 2048
#define HEAD_NUM 8
#define CHUNKS 8   // 1024-elem chunks per block; 8 independent loads in flight/wave

typedef float vfloat4 __attribute__((ext_vector_type(4)));
typedef int   vint4   __attribute__((ext_vector_type(4)));

// R7: output-linear mapping (proven best, 478us) + nt stores (neutral vs
// plain, R5/R6) + 8x work per wave. Theory: baseline waves move only
// 2KB each (1 dependent load -> 1 store -> endpgm), paying full load
// latency + store-drain per 2KB => ~2.3 TB/s effective vs the fill's
// 6.3 TB/s (fill waves loop, deep VMEM pipeline). 8 independent float4
// loads per thread issued back-to-back amortize wave setup/drain 8x and
// put 8x bytes in flight per wave. Mapping/stores otherwise identical.
// Super-chunk = 8192 consecutive output elements; every 8*ss region and
// every ss head-copy is a multiple of 8192, so a super-chunk never
// straddles a batch or head boundary (ss/8192 = 512,392,288,200,128,72,32,8).
__global__ __launch_bounds__(256) void genmask_kernel(
    const float* __restrict__ mask,   // (8, 1, 2048, 2048) f32
    int*         __restrict__ out)    // packed int32 0/1 (bool)
{
    // seq_lengths = {2048,1792,1536,1280,1024,768,512,256}
    constexpr unsigned int S[8]  = {2048u,1792u,1536u,1280u,1024u,768u,512u,256u};
    constexpr unsigned int SS[8] = {4194304u,3211264u,2359296u,1638400u,
                                    1048576u,589824u,262144u,65536u};
    // cumulative 8192-elem SUPER-chunks per batch region (8*ss/8192 each:
    // 4096,3136,2304,1600,1024,576,256,64 -> total 13056 blocks)
    constexpr unsigned int CS[8] = {0u,4096u,7232u,9536u,11136u,
                                    12160u,12736u,12992u};
    // cumulative output element offsets per batch region (8*ss each)
    constexpr unsigned long long ES[8] = {0ull,33554432ull,59244544ull,
        78118912ull,91226112ull,99614720ull,104333312ull,106430464ull};
    // exact magic for rem/s: i=(rem*M)>>40, M=floor(2^40/s)+1
    // (verified absmax=0 on full data in prior rounds, same rem domain [0,ss))
    constexpr unsigned long long MG[8] = {(1ull<<29)+1, 613566757ull,
        715827883ull, 858993460ull, (1ull<<30)+1, 1431655766ull,
        (1ull<<31)+1, (1ull<<32)+1};

    const unsigned int blk = blockIdx.x;

    // Branchless batch lookup on immediates (wave-uniform).
    int b = 0;
    #pragma unroll
    for (int t = 1; t < 8; ++t) b += (blk >= CS[t]) ? 1 : 0;

    const unsigned int s  = S[b];
    const unsigned int ss = SS[b];
    const unsigned long long M = MG[b];

    // Element base within this batch's output region [0, 8*ss).
    const unsigned int base = (blk - CS[b]) * 8192u;
    // base mod ss (<=7 uniform subtract steps; ss is a multiple of 8192).
    unsigned int rem_base = base;
    #pragma unroll
    for (int t = 0; t < HEAD_NUM - 1; ++t)
        if (rem_base >= ss) rem_base -= ss;

    const float* mb = mask + (size_t)b * MAX_SEQ * MAX_SEQ;

    // Phase 1: issue all CHUNKS independent loads back-to-back.
    vfloat4 v[CHUNKS];
    #pragma unroll
    for (int c = 0; c < CHUNKS; ++c) {
        const unsigned int rem = rem_base + c * 1024u + threadIdx.x * 4u;
        const unsigned int i = (unsigned int)(((unsigned long long)rem * M) >> 40);
        const unsigned int j = rem - i * s;      // multiple of 4
        v[c] = *(const vfloat4*)(mb + (size_t)i * MAX_SEQ + j);
    }

    // Phase 2: convert + nt store per chunk (output is linear: base + c*1024).
    const __half half_pt5 = __float2half(0.5f);
    int* op = out + ES[b] + base + threadIdx.x * 4u;
    #pragma unroll
    for (int c = 0; c < CHUNKS; ++c) {
        vint4 r;
        r.x = __hgt(__float2half(v[c].x), half_pt5) ? 1 : 0;
        r.y = __hgt(__float2half(v[c].y), half_pt5) ? 1 : 0;
        r.z = __hgt(__float2half(v[c].z), half_pt5) ? 1 : 0;
        r.w = __hgt(__float2half(v[c].w), half_pt5) ? 1 : 0;
        __builtin_nontemporal_store(r, (vint4*)(op + c * 1024u));
    }
}

extern "C" void kernel_launch(void* const* d_in, const int* in_sizes, int n_in,
                              void* d_out, int out_size, void* d_ws, size_t ws_size,
                              hipStream_t stream) {
    const float* mask = (const float*)d_in[0];
    int*         out  = (int*)d_out;

    // out_size = 106,954,752 elements; 8192 elements per block -> 13056 blocks.
    const unsigned int n_blocks = (unsigned int)(out_size / (1024 * CHUNKS));

    genmask_kernel<<<n_blocks, 256, 0, stream>>>(mask, out);
}